// Round 3
// baseline (316.128 us; speedup 1.0000x reference)
//
#include <hip/hip_runtime.h>

#define LSEQ 2048
#define EMB  512
#define NH   8
#define HD   64
#define NBATCH 4
// 1/sqrt(512) * log2(e): folded into Q projection; softmax runs in exp2 domain
#define QSCALE (0.044194173824159216f * 1.4426950408889634f)

using short8  = __attribute__((ext_vector_type(8))) short;
using short4v = __attribute__((ext_vector_type(4))) short;
using f32x4   = __attribute__((ext_vector_type(4))) float;

__device__ __forceinline__ short bf16r(float f) {
  union { float f; unsigned u; } x; x.f = f;
  unsigned r = x.u + 0x7FFFu + ((x.u >> 16) & 1u);
  return (short)(r >> 16);
}

__device__ __forceinline__ float exp2v(float x) {
  float r;
  asm("v_exp_f32 %0, %1" : "=v"(r) : "v"(x));   // D = 2^S0
  return r;
}

__device__ __forceinline__ short8 cvt8(const float* __restrict__ p) {
  float4 a = ((const float4*)p)[0];
  float4 b = ((const float4*)p)[1];
  short8 r;
  r[0]=bf16r(a.x); r[1]=bf16r(a.y); r[2]=bf16r(a.z); r[3]=bf16r(a.w);
  r[4]=bf16r(b.x); r[5]=bf16r(b.y); r[6]=bf16r(b.z); r[7]=bf16r(b.w);
  return r;
}

__device__ __forceinline__ short8 ld8(const short* __restrict__ p) {
  return *(const short8*)p;
}

// ---------------------------------------------------------------- Wo -> bf16
__global__ __launch_bounds__(256) void cvt_wo(const float* __restrict__ Wo,
                                              short* __restrict__ Wob) {
  int i = blockIdx.x * 256 + threadIdx.x;
  float4 v = ((const float4*)Wo)[i];
  short4v r;
  r[0]=bf16r(v.x); r[1]=bf16r(v.y); r[2]=bf16r(v.z); r[3]=bf16r(v.w);
  ((short4v*)Wob)[i] = r;
}

// ------------------------------------------------- per-head QKV projections
__global__ __launch_bounds__(256) void proj_kernel(
    const float* __restrict__ query, const float* __restrict__ keys,
    const float* __restrict__ values,
    const float* __restrict__ Wq, const float* __restrict__ Wk,
    const float* __restrict__ Wv,
    short* __restrict__ Qp, short* __restrict__ Kp, short* __restrict__ Vt) {
  int t = blockIdx.y;
  const float* x = (t == 0) ? query : (t == 1) ? keys : values;
  const float* W = (t == 0) ? Wq    : (t == 1) ? Wk   : Wv;
  int idx = blockIdx.x;
  int lt = idx & 31, h = (idx >> 5) & 7, n = idx >> 8;
  int tid = threadIdx.x, lane = tid & 63, w = tid >> 6;
  int row16 = lane & 15, g = lane >> 4;
  int lbase = lt * 64 + w * 16;

  const float* xr = x + ((size_t)(n * LSEQ + lbase + row16)) * EMB + h * HD + g * 8;
  short8 a0 = cvt8(xr);
  short8 a1 = cvt8(xr + 32);

  f32x4 acc[4];
#pragma unroll
  for (int et = 0; et < 4; et++) acc[et] = (f32x4){0.f, 0.f, 0.f, 0.f};
#pragma unroll
  for (int et = 0; et < 4; et++) {
    const float* wr = W + (size_t)(et * 16 + row16) * HD + g * 8;
    short8 b0 = cvt8(wr);
    short8 b1 = cvt8(wr + 32);
    acc[et] = __builtin_amdgcn_mfma_f32_16x16x32_bf16(a0, b0, acc[et], 0, 0, 0);
    acc[et] = __builtin_amdgcn_mfma_f32_16x16x32_bf16(a1, b1, acc[et], 0, 0, 0);
  }

  float sc = (t == 0) ? QSCALE : 1.f;
  if (t == 2) {  // V transposed: Vt[n][h][d][L]
#pragma unroll
    for (int et = 0; et < 4; et++)
#pragma unroll
      for (int r = 0; r < 4; r++) {
        int d = et * 16 + row16;
        int l = lbase + g * 4 + r;
        Vt[((size_t)((n * NH + h) * HD + d)) * LSEQ + l] = bf16r(acc[et][r]);
      }
  } else {
    short* O = (t == 0) ? Qp : Kp;
#pragma unroll
    for (int et = 0; et < 4; et++)
#pragma unroll
      for (int r = 0; r < 4; r++) {
        int l = lbase + g * 4 + r;
        O[((size_t)((n * NH + h) * LSEQ + l)) * HD + et * 16 + row16] =
            bf16r(acc[et][r] * sc);
      }
  }
}

// ------------------------------------------------------------ flash attention
// block = (n, h, qtile of 16); 4 waves SPLIT-K: wave w owns keys
// [w*512, (w+1)*512), 8 tiles of 64, independent online softmax per wave,
// merged via LDS at the end. Serial chain per wave = 8 iters (was 32).
union AttnSmem {
  short P[4][16][76];                       // per-wave P staging (loop phase)
  struct {
    float acc[4][16][68];                   // merge phase: per-wave O partials
    float ml[4][2][16];                     // [w][0]=m, [w][1]=l per row
  } mg;
};

__global__ __launch_bounds__(256) void attn_kernel(
    const short* __restrict__ Qp, const short* __restrict__ Kp,
    const short* __restrict__ Vt, const int* __restrict__ mask,
    short* __restrict__ aout) {
  __shared__ AttnSmem sm;

  int idx = blockIdx.x;
  int qt = idx & 127, h = (idx >> 7) & 7, n = idx >> 10;
  int tid = threadIdx.x, lane = tid & 63, w = tid >> 6;
  int row16 = lane & 15, g = lane >> 4;

  size_t nh = (size_t)(n * NH + h);
  const short* Qb = Qp + (nh * LSEQ + qt * 16) * HD;
  short8 aq0 = ld8(Qb + row16 * HD + g * 8);
  short8 aq1 = ld8(Qb + row16 * HD + 32 + g * 8);

  f32x4 acc[4];
#pragma unroll
  for (int dt = 0; dt < 4; dt++) acc[dt] = (f32x4){0.f, 0.f, 0.f, 0.f};
  float m[4], lsum[4];
#pragma unroll
  for (int r = 0; r < 4; r++) { m[r] = -3e38f; lsum[r] = 0.f; }

  const short* Kb0 = Kp + nh * LSEQ * HD;
  const short* Vb0 = Vt + nh * HD * LSEQ;
  const int* mb = mask + n * LSEQ + w * 512;

  for (int kt = 0; kt < 8; kt++) {
    int kb = w * 512 + kt * 64;
    short8 kf0[4], kf1[4], vf0[4], vf1[4];
#pragma unroll
    for (int ks = 0; ks < 4; ks++) {
      const short* Kb = Kb0 + (size_t)(kb + ks * 16 + row16) * HD + g * 8;
      kf0[ks] = ld8(Kb);
      kf1[ks] = ld8(Kb + 32);
    }
#pragma unroll
    for (int dt = 0; dt < 4; dt++) {
      const short* Vb = Vb0 + (size_t)(dt * 16 + row16) * LSEQ + kb + g * 8;
      vf0[dt] = ld8(Vb);
      vf1[dt] = ld8(Vb + 32);
    }
    int mk[4];
#pragma unroll
    for (int ks = 0; ks < 4; ks++) mk[ks] = mb[kt * 64 + ks * 16 + row16];

    // ---- S = Q K^T (16q x 64k)
    f32x4 s[4];
    __builtin_amdgcn_s_setprio(1);
#pragma unroll
    for (int ks = 0; ks < 4; ks++) {
      f32x4 t = (f32x4){0.f, 0.f, 0.f, 0.f};
      t = __builtin_amdgcn_mfma_f32_16x16x32_bf16(aq0, kf0[ks], t, 0, 0, 0);
      t = __builtin_amdgcn_mfma_f32_16x16x32_bf16(aq1, kf1[ks], t, 0, 0, 0);
      s[ks] = t;
    }
    __builtin_amdgcn_s_setprio(0);

#pragma unroll
    for (int ks = 0; ks < 4; ks++)
#pragma unroll
      for (int r = 0; r < 4; r++)
        s[ks][r] = mk[ks] ? s[ks][r] : -1e30f;

    float tmax[4];
#pragma unroll
    for (int r = 0; r < 4; r++)
      tmax[r] = fmaxf(fmaxf(s[0][r], s[1][r]), fmaxf(s[2][r], s[3][r]));
#pragma unroll
    for (int off = 1; off < 16; off <<= 1)
#pragma unroll
      for (int r = 0; r < 4; r++)
        tmax[r] = fmaxf(tmax[r], __shfl_xor(tmax[r], off));

    // defer-max rescale (T13); taken on first iter since m = -3e38
    int grew = !((tmax[0] <= m[0] + 8.f) & (tmax[1] <= m[1] + 8.f) &
                 (tmax[2] <= m[2] + 8.f) & (tmax[3] <= m[3] + 8.f));
    if (__any(grew)) {
#pragma unroll
      for (int r = 0; r < 4; r++) {
        float mn = fmaxf(m[r], tmax[r]);
        float sf = exp2v(m[r] - mn);
        lsum[r] *= sf;
        m[r] = mn;
#pragma unroll
        for (int dt = 0; dt < 4; dt++) acc[dt][r] *= sf;
      }
    }

    float ps[4];
#pragma unroll
    for (int r = 0; r < 4; r++) ps[r] = 0.f;
#pragma unroll
    for (int ks = 0; ks < 4; ks++)
#pragma unroll
      for (int r = 0; r < 4; r++) {
        float p = exp2v(s[ks][r] - m[r]);
        ps[r] += p;
        sm.P[w][g * 4 + r][ks * 16 + row16] = bf16r(p);
      }
#pragma unroll
    for (int off = 1; off < 16; off <<= 1)
#pragma unroll
      for (int r = 0; r < 4; r++) ps[r] += __shfl_xor(ps[r], off);
#pragma unroll
    for (int r = 0; r < 4; r++) lsum[r] += ps[r];

    short8 ap0 = ld8(&sm.P[w][row16][g * 8]);
    short8 ap1 = ld8(&sm.P[w][row16][32 + g * 8]);
    __builtin_amdgcn_s_setprio(1);
#pragma unroll
    for (int dt = 0; dt < 4; dt++) {
      acc[dt] = __builtin_amdgcn_mfma_f32_16x16x32_bf16(ap0, vf0[dt], acc[dt], 0, 0, 0);
      acc[dt] = __builtin_amdgcn_mfma_f32_16x16x32_bf16(ap1, vf1[dt], acc[dt], 0, 0, 0);
    }
    __builtin_amdgcn_s_setprio(0);
  }

  // ---- merge the 4 waves' partial (m, l, acc) --------------------------
  __syncthreads();                     // all waves done with sm.P
#pragma unroll
  for (int dt = 0; dt < 4; dt++)
#pragma unroll
    for (int r = 0; r < 4; r++)
      sm.mg.acc[w][g * 4 + r][dt * 16 + row16] = acc[dt][r];
  if (row16 == 0) {
#pragma unroll
    for (int r = 0; r < 4; r++) {
      sm.mg.ml[w][0][g * 4 + r] = m[r];
      sm.mg.ml[w][1][g * 4 + r] = lsum[r];
    }
  }
  __syncthreads();

  // wave w combines rows [w*4, w*4+4): lane -> row = w*4 + (lane>>4)
  int row = w * 4 + (lane >> 4);
  float mw[4], lw[4];
#pragma unroll
  for (int wv = 0; wv < 4; wv++) {
    mw[wv] = sm.mg.ml[wv][0][row];
    lw[wv] = sm.mg.ml[wv][1][row];
  }
  float M = fmaxf(fmaxf(mw[0], mw[1]), fmaxf(mw[2], mw[3]));
  float sf[4], L = 0.f;
#pragma unroll
  for (int wv = 0; wv < 4; wv++) {
    sf[wv] = exp2v(mw[wv] - M);
    L += sf[wv] * lw[wv];
  }
  float inv = L > 0.f ? 1.f / L : 0.f;
  int q = qt * 16 + row;
#pragma unroll
  for (int j = 0; j < 4; j++) {
    int col = j * 16 + row16;
    float o = sf[0] * sm.mg.acc[0][row][col] + sf[1] * sm.mg.acc[1][row][col] +
              sf[2] * sm.mg.acc[2][row][col] + sf[3] * sm.mg.acc[3][row][col];
    aout[((size_t)(n * LSEQ + q)) * EMB + h * HD + col] = bf16r(o * inv);
  }
}

// --------------------------------------------------- final projection + bias
__global__ __launch_bounds__(256) void outproj_kernel(
    const short* __restrict__ aout, const short* __restrict__ Wob,
    const float* __restrict__ bo, float* __restrict__ out) {
  int mt = blockIdx.x, nt = blockIdx.y;
  int tid = threadIdx.x, lane = tid & 63, w = tid >> 6;
  int row16 = lane & 15, g = lane >> 4;
  int mrow = mt * 64 + w * 16;

  f32x4 acc[4];
#pragma unroll
  for (int et = 0; et < 4; et++) acc[et] = (f32x4){0.f, 0.f, 0.f, 0.f};

  for (int kc = 0; kc < 16; kc++) {
    short8 a = ld8(aout + (size_t)(mrow + row16) * EMB + kc * 32 + g * 8);
#pragma unroll
    for (int et = 0; et < 4; et++) {
      short8 b = ld8(Wob + (size_t)(nt * 64 + et * 16 + row16) * EMB + kc * 32 + g * 8);
      acc[et] = __builtin_amdgcn_mfma_f32_16x16x32_bf16(a, b, acc[et], 0, 0, 0);
    }
  }
#pragma unroll
  for (int et = 0; et < 4; et++) {
    int e = nt * 64 + et * 16 + row16;
    float bias = bo[e];
#pragma unroll
    for (int r = 0; r < 4; r++) {
      int row = mrow + g * 4 + r;
      out[(size_t)row * EMB + e] = acc[et][r] + bias;
    }
  }
}

extern "C" void kernel_launch(void* const* d_in, const int* in_sizes, int n_in,
                              void* d_out, int out_size, void* d_ws, size_t ws_size,
                              hipStream_t stream) {
  const float* values = (const float*)d_in[0];
  const float* keys   = (const float*)d_in[1];
  const float* query  = (const float*)d_in[2];
  const int*   mask   = (const int*)d_in[3];
  const float* Wv     = (const float*)d_in[4];
  const float* Wk     = (const float*)d_in[5];
  const float* Wq     = (const float*)d_in[6];
  const float* Wo     = (const float*)d_in[7];
  const float* bo     = (const float*)d_in[8];
  float* out = (float*)d_out;

  // Qp/Kp scratch in d_out (16 MB, overwritten by outproj last; stream-ordered)
  short* Qp = (short*)d_out;
  short* Kp = (short*)((char*)d_out + (8u << 20));
  char* ws = (char*)d_ws;
  short* Vt   = (short*)(ws);                  //  8 MB  [n][h][64][2048]
  short* aout = (short*)(ws + (8u << 20));     //  8 MB  [n*2048][512]
  short* Wob  = (short*)(ws + (16u << 20));    // 0.5 MB

  cvt_wo<<<256, 256, 0, stream>>>(Wo, Wob);
  proj_kernel<<<dim3(NBATCH * NH * (LSEQ / 64), 3), 256, 0, stream>>>(
      query, keys, values, Wq, Wk, Wv, Qp, Kp, Vt);
  attn_kernel<<<NBATCH * NH * (LSEQ / 16), 256, 0, stream>>>(Qp, Kp, Vt, mask, aout);
  outproj_kernel<<<dim3((NBATCH * LSEQ) / 64, EMB / 64), 256, 0, stream>>>(
      aout, Wob, bo, out);
}